// Round 15
// baseline (138.082 us; speedup 1.0000x reference)
//
#include <hip/hip_runtime.h>

// LambdaLayer b=4, m=256 spatial, cin=1024, heads=4, dim_k=dim_v=256, u=1.
// f32 in/out; bf16 MFMA compute, f32 accum. LDS XOR-swizzle (granule^=row&7).
// R15: persistent-kernel fusion. 2 launches:
//   prep  (R14 version; also zeroes grid-barrier counters)
//   fused (proj 768 jobs | gridbar | lc_s 1088 jobs | gridbar | yfinal 512)
// Grid 512x256, LDS 40KB (4 blk/CU cap), launch_bounds(256,2) -> co-resident.
// Barrier: device-scope atomicAdd + __threadfence (L2 wb/inv across XCDs).

typedef __bf16 bf16;
typedef __attribute__((ext_vector_type(8))) __bf16 bf16x8;
typedef __attribute__((ext_vector_type(4))) float f32x4;

#define NBLK 512u

__device__ __forceinline__ bf16x8 ld8(const bf16* p) {
    return *reinterpret_cast<const bf16x8*>(p);
}

__device__ __forceinline__ void gridbar(unsigned int* cnt) {
    __syncthreads();                 // block's stores drained (vmcnt at barrier)
    if (threadIdx.x == 0) {
        __threadfence();             // release: L2 writeback to coherent point
        atomicAdd(cnt, 1u);
        while (atomicAdd(cnt, 0u) < NBLK) __builtin_amdgcn_s_sleep(8);
        __threadfence();             // acquire: invalidate L1/L2
    }
    __syncthreads();
}

// ---------------- prep: casts + weight transposes + counter zero -----------
__global__ __launch_bounds__(256) void prep(
    const float* __restrict__ x, const float* __restrict__ Wq,
    const float* __restrict__ Wk, const float* __restrict__ Wv,
    const float* __restrict__ rpe, bf16* __restrict__ xb,
    bf16* __restrict__ WqT, bf16* __restrict__ WkT, bf16* __restrict__ WvT,
    bf16* __restrict__ rpeb, unsigned int* cnt) {
    __shared__ float tile[32][33];
    const int bid = blockIdx.x, tid = threadIdx.x;
    if (bid == 0 && tid < 2) cnt[tid * 16] = 0u;  // zero barrier counters
    const float* W = nullptr;
    bf16* WT = nullptr;
    int ldw = 0, ci = 0, di = 0;
    if (bid < 1024) {
        W = Wq; WT = WqT; ldw = 1024; ci = bid >> 5; di = bid & 31;
    } else if (bid < 1280) {
        const int t2 = bid - 1024;
        W = Wk; WT = WkT; ldw = 256; ci = t2 >> 3; di = t2 & 7;
    } else if (bid < 1536) {
        const int t2 = bid - 1280;
        W = Wv; WT = WvT; ldw = 256; ci = t2 >> 3; di = t2 & 7;
    }
    if (W) {  // transpose-cast one 32x32 tile
        const int r = tid >> 3, c4 = (tid & 7) * 4;
        const float4 v =
            *reinterpret_cast<const float4*>(&W[(ci * 32 + r) * ldw + di * 32 + c4]);
        tile[r][c4 + 0] = v.x;
        tile[r][c4 + 1] = v.y;
        tile[r][c4 + 2] = v.z;
        tile[r][c4 + 3] = v.w;
        __syncthreads();
        bf16 o[4] = {(bf16)tile[c4 + 0][r], (bf16)tile[c4 + 1][r],
                     (bf16)tile[c4 + 2][r], (bf16)tile[c4 + 3][r]};
        *reinterpret_cast<uint2*>(&WT[(di * 32 + r) * 1024 + ci * 32 + c4]) =
            *reinterpret_cast<uint2*>(o);
        return;
    }
    if (bid < 1792) {  // xb cast
        const int base = (bid - 1536) * 1024 + tid;
        const float4* xs = reinterpret_cast<const float4*>(x);
#pragma unroll
        for (int j = 0; j < 4; ++j) {
            const float4 v = xs[base + j * 256];
            bf16 o[4] = {(bf16)v.x, (bf16)v.y, (bf16)v.z, (bf16)v.w};
            *reinterpret_cast<uint2*>(&xb[(base + j * 256) * 4]) =
                *reinterpret_cast<uint2*>(o);
        }
        return;
    }
    {  // rpeb cast
        const int base = (bid - 1792) * 1024 + tid;
        const float4* rs = reinterpret_cast<const float4*>(rpe);
#pragma unroll
        for (int j = 0; j < 4; ++j) {
            const int idx = base + j * 256;
            if (idx < 61504) {
                const float4 v = rs[idx];
                bf16 o[4] = {(bf16)v.x, (bf16)v.y, (bf16)v.z, (bf16)v.w};
                *reinterpret_cast<uint2*>(&rpeb[idx * 4]) =
                    *reinterpret_cast<uint2*>(o);
            }
        }
    }
}

// ---- MFMA K-pass, 32x64 tile, BK=128, 4 waves (R12-proven) ----------------
template <int PA, int PB>
__device__ __forceinline__ void kpass128(const bf16* __restrict__ Ap, int offA,
                                         const bf16* __restrict__ Bp,
                                         bf16* __restrict__ Al, bf16* __restrict__ Bl,
                                         f32x4 (&acc)[2], int m0, int n0,
                                         int nsteps) {
    const int tid = threadIdx.x;
    const int w = tid >> 6, l = tid & 63;
    const int sr = tid >> 4;
    const int sg = tid & 15;
    const int wrow = (w & 1) * 16, wcol = (w >> 1) * 32;
    const int fr = l & 15, fg = l >> 4;
    const int fx7 = fr & 7;
    const int st = sr * 128 + ((sg ^ (sr & 7)) << 3);
    const bf16* asrc0 = Ap + (m0 + sr) * PA + offA + sg * 8;
    const bf16* asrc1 = asrc0 + 16 * PA;
    const bf16* bsrc0 = Bp + (n0 + sr) * PB + sg * 8;
    const bf16* bsrc1 = bsrc0 + 16 * PB;
    const bf16* bsrc2 = bsrc0 + 32 * PB;
    const bf16* bsrc3 = bsrc0 + 48 * PB;

    bf16x8 a0 = ld8(asrc0), a1 = ld8(asrc1);
    bf16x8 b0 = ld8(bsrc0), b1 = ld8(bsrc1), b2 = ld8(bsrc2), b3 = ld8(bsrc3);
    for (int kt = 0; kt < nsteps; ++kt) {
        __syncthreads();
        *reinterpret_cast<bf16x8*>(&Al[st]) = a0;
        *reinterpret_cast<bf16x8*>(&Al[st + 2048]) = a1;
        *reinterpret_cast<bf16x8*>(&Bl[st]) = b0;
        *reinterpret_cast<bf16x8*>(&Bl[st + 2048]) = b1;
        *reinterpret_cast<bf16x8*>(&Bl[st + 4096]) = b2;
        *reinterpret_cast<bf16x8*>(&Bl[st + 6144]) = b3;
        __syncthreads();
        if (kt + 1 < nsteps) {
            const int k0 = (kt + 1) * 128;
            a0 = ld8(asrc0 + k0);
            a1 = ld8(asrc1 + k0);
            b0 = ld8(bsrc0 + k0);
            b1 = ld8(bsrc1 + k0);
            b2 = ld8(bsrc2 + k0);
            b3 = ld8(bsrc3 + k0);
        }
#pragma unroll
        for (int ks = 0; ks < 4; ++ks) {
            const int eo = ((ks * 4 + fg) ^ fx7) << 3;
            const bf16x8 af = ld8(&Al[(wrow + fr) * 128 + eo]);
            const bf16x8 bg0 = ld8(&Bl[(wcol + fr) * 128 + eo]);
            const bf16x8 bg1 = ld8(&Bl[(wcol + 16 + fr) * 128 + eo]);
            acc[0] = __builtin_amdgcn_mfma_f32_16x16x32_bf16(af, bg0, acc[0], 0, 0, 0);
            acc[1] = __builtin_amdgcn_mfma_f32_16x16x32_bf16(af, bg1, acc[1], 0, 0, 0);
        }
    }
}

// --------------- fused persistent kernel: proj | lc_s | yfinal -------------
__global__ __launch_bounds__(256, 2) void fused(
    const bf16* __restrict__ xb, const bf16* __restrict__ WqT,
    const bf16* __restrict__ WkT, const bf16* __restrict__ WvT,
    const float* __restrict__ qg, const float* __restrict__ qb,
    const float* __restrict__ qm, const float* __restrict__ qv,
    const float* __restrict__ vg, const float* __restrict__ vb,
    const float* __restrict__ vm, const float* __restrict__ vvar,
    bf16* __restrict__ Q2, float* __restrict__ kn, bf16* __restrict__ vbn,
    const bf16* __restrict__ rpeb, bf16* __restrict__ LcT, bf16* __restrict__ S,
    float* __restrict__ out, unsigned int* cnt) {
    __shared__ __align__(16) char smem_raw[40960];
    const int bid = blockIdx.x;
    const int tid = threadIdx.x;
    const int w = tid >> 6, l = tid & 63;

    // ================= phase 1: proj (768 jobs) =================
    for (int j = bid; j < 768; j += NBLK) {
        bf16* Al = (bf16*)smem_raw;            // 8 KB
        bf16* Bl = (bf16*)(smem_raw + 8192);   // 16 KB
        const int z = j >> 7;
        const int m0 = ((j >> 2) & 31) * 32;
        const int bx = j & 3;
        int n0, mode;
        const bf16* Bg;
        if (z < 4) { mode = 0; Bg = WqT; n0 = (z * 4 + bx) * 64; }
        else if (z == 4) { mode = 1; Bg = WkT; n0 = bx * 64; }
        else { mode = 2; Bg = WvT; n0 = bx * 64; }
        f32x4 acc[2] = {};
        kpass128<1024, 1024>(xb, 0, Bg, Al, Bl, acc, m0, n0, 8);

        const int wrow = (w & 1) * 16, wcol = (w >> 1) * 32;
        const int drow = (l >> 4) * 4, dcol = l & 15;
#pragma unroll
        for (int ns = 0; ns < 2; ++ns) {
            const int gc = n0 + wcol + ns * 16 + dcol;
            float scale = 1.f, shift = 0.f;
            if (mode == 0) {
                scale = qg[gc] * rsqrtf(qv[gc] + 1e-3f);
                shift = qb[gc] - qm[gc] * scale;
            } else if (mode == 2) {
                scale = vg[gc] * rsqrtf(vvar[gc] + 1e-3f);
                shift = vb[gc] - vm[gc] * scale;
            }
#pragma unroll
            for (int r = 0; r < 4; ++r) {
                const int gr = m0 + wrow + drow + r;
                const float val = acc[ns][r] * scale + shift;
                if (mode == 0) {
                    const int bh = gr >> 6;
                    const int kk = (gr & 63) * 4 + (gc >> 8);
                    Q2[bh * 65536 + (gc & 255) * 256 + kk] = (bf16)val;
                } else if (mode == 1) {
                    kn[gr * 256 + gc] = val;
                } else {
                    vbn[gr * 256 + gc] = (bf16)val;
                }
            }
        }
        __syncthreads();  // LDS reuse safety across jobs
    }
    gridbar(cnt);

    // ================= phase 2: lc_s (1088 jobs) =================
    for (int j = bid; j < 1088; j += NBLK) {
        bf16* smem = (bf16*)smem_raw;
        const int jx = j & 3, jy = j >> 2;
        const int fr = l & 15, fk = (l >> 4) * 8;
        const int fx = (fr & 7) << 3;

        if (jy < 16) {  // LC
            const int b = jy >> 2;
            const int m0v = (jy & 3) * 64;
            const int n0k = jx * 64;
            bf16* Bfull = smem;
            bf16* Al = smem + 16384;

            const float* knb = kn + (b * 256 + n0k) * 256;
            const int row = tid >> 2, cq = (tid & 3) * 4;
            const float* src = knb + row * 256;
            float mx = -3.4e38f;
#pragma unroll
            for (int i = 0; i < 16; ++i) {
                const float4 v = *reinterpret_cast<const float4*>(&src[cq + i * 16]);
                mx = fmaxf(fmaxf(fmaxf(v.x, v.y), fmaxf(v.z, v.w)), mx);
            }
            mx = fmaxf(mx, __shfl_xor(mx, 1));
            mx = fmaxf(mx, __shfl_xor(mx, 2));
            float sum = 0.f;
#pragma unroll
            for (int i = 0; i < 16; ++i) {
                const float4 v = *reinterpret_cast<const float4*>(&src[cq + i * 16]);
                sum += expf(v.x - mx) + expf(v.y - mx) + expf(v.z - mx) + expf(v.w - mx);
            }
            sum += __shfl_xor(sum, 1);
            sum += __shfl_xor(sum, 2);
            const float inv = 1.f / sum;
#pragma unroll
            for (int i = 0; i < 16; ++i) {
                const int col = cq + i * 16;
                const float4 v = *reinterpret_cast<const float4*>(&src[col]);
                bf16 o[4] = {(bf16)(expf(v.x - mx) * inv), (bf16)(expf(v.y - mx) * inv),
                             (bf16)(expf(v.z - mx) * inv), (bf16)(expf(v.w - mx) * inv)};
                const int elem =
                    row * 256 + ((((col >> 3) ^ (row & 7)) << 3) | (col & 7));
                *reinterpret_cast<uint2*>(&Bfull[elem]) = *reinterpret_cast<uint2*>(o);
            }

            const int sr0 = tid >> 3, sg = tid & 7;
            const int st0 = sr0 * 64 + ((sg ^ (sr0 & 7)) << 3);
            const int st1 = (sr0 + 32) * 64 + ((sg ^ (sr0 & 7)) << 3);
            const int wr = (w >> 1) * 32, wc = (w & 1) * 32;
            const bf16* va0 = vbn + (b * 256 + m0v + sr0) * 256 + sg * 8;
            const bf16* va1 = va0 + 32 * 256;
            bf16x8 a0 = ld8(va0), a1 = ld8(va1);
            f32x4 acc[2][2] = {};
            for (int kt = 0; kt < 4; ++kt) {
                __syncthreads();
                *reinterpret_cast<bf16x8*>(&Al[st0]) = a0;
                *reinterpret_cast<bf16x8*>(&Al[st1]) = a1;
                __syncthreads();
                if (kt + 1 < 4) {
                    a0 = ld8(va0 + (kt + 1) * 64);
                    a1 = ld8(va1 + (kt + 1) * 64);
                }
#pragma unroll
                for (int ks = 0; ks < 2; ++ks) {
                    const int eoA = (ks * 32 + fk) ^ fx;
                    const int eoB = (kt * 64 + ks * 32 + fk) ^ fx;
                    const bf16x8 af0 = ld8(&Al[(wr + fr) * 64 + eoA]);
                    const bf16x8 af1 = ld8(&Al[(wr + 16 + fr) * 64 + eoA]);
                    const bf16x8 bg0 = ld8(&Bfull[(wc + fr) * 256 + eoB]);
                    const bf16x8 bg1 = ld8(&Bfull[(wc + 16 + fr) * 256 + eoB]);
                    acc[0][0] = __builtin_amdgcn_mfma_f32_16x16x32_bf16(af0, bg0, acc[0][0], 0, 0, 0);
                    acc[0][1] = __builtin_amdgcn_mfma_f32_16x16x32_bf16(af0, bg1, acc[0][1], 0, 0, 0);
                    acc[1][0] = __builtin_amdgcn_mfma_f32_16x16x32_bf16(af1, bg0, acc[1][0], 0, 0, 0);
                    acc[1][1] = __builtin_amdgcn_mfma_f32_16x16x32_bf16(af1, bg1, acc[1][1], 0, 0, 0);
                }
            }
            const int drow = (l >> 4) * 4, dcol = l & 15;
#pragma unroll
            for (int ms = 0; ms < 2; ++ms)
#pragma unroll
                for (int ns = 0; ns < 2; ++ns)
#pragma unroll
                    for (int r = 0; r < 4; ++r)
                        LcT[b * 65536 + (m0v + wr + ms * 16 + drow + r) * 256 + n0k +
                            wc + ns * 16 + dcol] = (bf16)acc[ms][ns][r];
        } else {  // S
            const int n = jy - 16;
            const int m0 = jx * 64;
            const int in_ = n >> 4, jn = n & 15;
            bf16* Als = smem;
            bf16* Bls = smem + 16384;
#pragma unroll
            for (int i = 0; i < 2; ++i) {
                const int slot = tid + i * 256;
                const int row = slot >> 5, g = slot & 31;
                *reinterpret_cast<bf16x8*>(&Bls[row * 256 + ((g ^ (row & 7)) << 3)]) =
                    ld8(Q2 + row * 65536 + n * 256 + g * 8);
            }
#pragma unroll
            for (int i = 0; i < 8; ++i) {
                const int slot = tid + i * 256;
                const int row = slot >> 5, g = slot & 31;
                const int m = m0 + row;
                const int ridx = ((m >> 4) - in_ + 15) * 31 + ((m & 15) - jn + 15);
                *reinterpret_cast<bf16x8*>(&Als[row * 256 + ((g ^ (row & 7)) << 3)]) =
                    ld8(rpeb + ridx * 256 + g * 8);
            }
            __syncthreads();
            f32x4 acc = {};
#pragma unroll
            for (int ks = 0; ks < 8; ++ks) {
                const int eo = (ks * 32 + fk) ^ fx;
                const bf16x8 af = ld8(&Als[(w * 16 + fr) * 256 + eo]);
                const bf16x8 bg = ld8(&Bls[fr * 256 + eo]);
                acc = __builtin_amdgcn_mfma_f32_16x16x32_bf16(af, bg, acc, 0, 0, 0);
            }
            const int drow = (l >> 4) * 4, bh = l & 15;
#pragma unroll
            for (int r = 0; r < 4; ++r) {
                const int m = m0 + w * 16 + drow + r;
                S[n * 4096 + bh * 256 + m] = (bf16)acc[r];
            }
        }
        __syncthreads();  // LDS reuse safety across jobs
    }
    gridbar(cnt + 16);

    // ================= phase 3: yfinal (512 jobs) =================
    for (int j = bid; j < 512; j += NBLK) {
        bf16* Al = (bf16*)smem_raw;            // 8 KB
        bf16* Bl = (bf16*)(smem_raw + 8192);   // 16 KB
        const int m0 = ((j >> 2) & 7) * 32, n0 = (j & 3) * 64;
        const int z = j >> 5;
        f32x4 acc[2] = {};
        kpass128<256, 256>(Q2 + z * 65536, 0, LcT + (z >> 2) * 65536, Al, Bl, acc,
                           m0, n0, 2);
        kpass128<4096, 256>(S, z * 256, vbn + (z >> 2) * 65536, Al, Bl, acc, m0,
                            n0, 2);

        const int wrow = (w & 1) * 16, wcol = (w >> 1) * 32;
        const int drow = (l >> 4) * 4, dcol = l & 15;
#pragma unroll
        for (int ns = 0; ns < 2; ++ns)
#pragma unroll
            for (int r = 0; r < 4; ++r)
                out[(z >> 2) * 262144 + (m0 + wrow + drow + r) * 1024 +
                    (z & 3) * 256 + n0 + wcol + ns * 16 + dcol] = acc[ns][r];
    }
}

extern "C" void kernel_launch(void* const* d_in, const int* in_sizes, int n_in,
                              void* d_out, int out_size, void* d_ws, size_t ws_size,
                              hipStream_t stream) {
    const float* x = (const float*)d_in[0];
    const float* Wq = (const float*)d_in[1];
    const float* Wk = (const float*)d_in[2];
    const float* Wv = (const float*)d_in[3];
    const float* qg = (const float*)d_in[4];
    const float* qb = (const float*)d_in[5];
    const float* qm = (const float*)d_in[6];
    const float* qv = (const float*)d_in[7];
    const float* vg = (const float*)d_in[8];
    const float* vb = (const float*)d_in[9];
    const float* vm = (const float*)d_in[10];
    const float* vvar = (const float*)d_in[11];
    const float* rpe = (const float*)d_in[12];
    float* out = (float*)d_out;

    char* wsb = (char*)d_ws;
    bf16* xb = (bf16*)(wsb);                  // 2 MB
    bf16* WqT = (bf16*)(wsb + 0x200000u);     // 2 MB
    bf16* WkT = (bf16*)(wsb + 0x400000u);     // 512 KB
    bf16* WvT = (bf16*)(wsb + 0x480000u);     // 512 KB
    bf16* rpeb = (bf16*)(wsb + 0x500000u);    // 492 KB (region ends 0x57B200)
    unsigned int* cnt = (unsigned int*)(wsb + 0x57F000u);  // barrier counters
    bf16* Q2 = (bf16*)(wsb + 0x580000u);      // 2 MB
    bf16* vbn = (bf16*)(wsb + 0x800000u);     // 512 KB
    bf16* LcT = (bf16*)(wsb + 0x880000u);     // 512 KB
    bf16* S = (bf16*)(wsb + 0x900000u);       // 2 MB
    float* kn = (float*)(wsb + 0xB00000u);    // 1 MB

    const dim3 blk(256);
    prep<<<1853, blk, 0, stream>>>(x, Wq, Wk, Wv, rpe, xb, WqT, WkT, WvT, rpeb,
                                   cnt);
    fused<<<NBLK, blk, 0, stream>>>(xb, WqT, WkT, WvT, qg, qb, qm, qv, vg, vb, vm,
                                    vvar, Q2, kn, vbn, rpeb, LcT, S, out, cnt);
}

// Round 16
// 41.198 us; speedup vs baseline: 3.3517x; 3.3517x over previous
//
#include <hip/hip_runtime.h>

// LambdaLayer b=4, m=256 spatial, cin=1024, heads=4, dim_k=dim_v=256, u=1.
// f32 in/out; bf16 MFMA compute, f32 accum. LDS XOR-swizzle (granule^=row&7).
// R16 = R14 (best 39.9us) with xb eliminated: proj stages x directly from f32
// with in-register bf16 cvt (isolated test; R8 bundled it with a bad tile).
// R15 lesson: persistent fusion + atomic-spin gridbar = 55us/barrier, dead.
// 4 launches: prep(no xb) -> proj_all -> lc_s -> yfinal.

typedef __bf16 bf16;
typedef __attribute__((ext_vector_type(8))) __bf16 bf16x8;
typedef __attribute__((ext_vector_type(4))) float f32x4;

__device__ __forceinline__ bf16x8 ld8(const bf16* p) {
    return *reinterpret_cast<const bf16x8*>(p);
}
__device__ __forceinline__ bf16x8 cvt8(const float4 u0, const float4 u1) {
    bf16 o[8] = {(bf16)u0.x, (bf16)u0.y, (bf16)u0.z, (bf16)u0.w,
                 (bf16)u1.x, (bf16)u1.y, (bf16)u1.z, (bf16)u1.w};
    return *reinterpret_cast<bf16x8*>(o);
}

// ------------- prep: weight transposes + rpe cast (no xb) ------------------
// grid 1597: [0,1024) Wq; [1024,1280) Wk; [1280,1536) Wv; [1536,1597) rpe
__global__ __launch_bounds__(256) void prep(
    const float* __restrict__ Wq, const float* __restrict__ Wk,
    const float* __restrict__ Wv, const float* __restrict__ rpe,
    bf16* __restrict__ WqT, bf16* __restrict__ WkT, bf16* __restrict__ WvT,
    bf16* __restrict__ rpeb) {
    __shared__ float tile[32][33];
    const int bid = blockIdx.x, tid = threadIdx.x;
    const float* W = nullptr;
    bf16* WT = nullptr;
    int ldw = 0, ci = 0, di = 0;
    if (bid < 1024) {
        W = Wq; WT = WqT; ldw = 1024; ci = bid >> 5; di = bid & 31;
    } else if (bid < 1280) {
        const int t2 = bid - 1024;
        W = Wk; WT = WkT; ldw = 256; ci = t2 >> 3; di = t2 & 7;
    } else if (bid < 1536) {
        const int t2 = bid - 1280;
        W = Wv; WT = WvT; ldw = 256; ci = t2 >> 3; di = t2 & 7;
    }
    if (W) {  // transpose-cast one 32x32 tile
        const int r = tid >> 3, c4 = (tid & 7) * 4;
        const float4 v =
            *reinterpret_cast<const float4*>(&W[(ci * 32 + r) * ldw + di * 32 + c4]);
        tile[r][c4 + 0] = v.x;
        tile[r][c4 + 1] = v.y;
        tile[r][c4 + 2] = v.z;
        tile[r][c4 + 3] = v.w;
        __syncthreads();
        bf16 o[4] = {(bf16)tile[c4 + 0][r], (bf16)tile[c4 + 1][r],
                     (bf16)tile[c4 + 2][r], (bf16)tile[c4 + 3][r]};
        *reinterpret_cast<uint2*>(&WT[(di * 32 + r) * 1024 + ci * 32 + c4]) =
            *reinterpret_cast<uint2*>(o);
        return;
    }
    {  // rpeb cast
        const int base = (bid - 1536) * 1024 + tid;
        const float4* rs = reinterpret_cast<const float4*>(rpe);
#pragma unroll
        for (int j = 0; j < 4; ++j) {
            const int idx = base + j * 256;
            if (idx < 61504) {
                const float4 v = rs[idx];
                bf16 o[4] = {(bf16)v.x, (bf16)v.y, (bf16)v.z, (bf16)v.w};
                *reinterpret_cast<uint2*>(&rpeb[idx * 4]) =
                    *reinterpret_cast<uint2*>(o);
            }
        }
    }
}

// ---- MFMA K-pass, 32x64 tile, BK=128, 4 waves; A from f32 (cvt on stage) --
// A:[32][128] LDS 8KB, B:[64][128] 16KB, swizzled (granule ^= row&7).
// Wave w: rows (w&1)*16, cols (w>>1)*32. 8 MFMA/wave/step.
__device__ __forceinline__ void kpass128f(const float* __restrict__ Af,
                                          const bf16* __restrict__ Bp,
                                          bf16* __restrict__ Al, bf16* __restrict__ Bl,
                                          f32x4 (&acc)[2], int m0, int n0,
                                          int nsteps) {
    const int tid = threadIdx.x;
    const int w = tid >> 6, l = tid & 63;
    const int sr = tid >> 4;   // staging row 0..15
    const int sg = tid & 15;   // granule 0..15
    const int wrow = (w & 1) * 16, wcol = (w >> 1) * 32;
    const int fr = l & 15, fg = l >> 4;
    const int fx7 = fr & 7;
    const int st = sr * 128 + ((sg ^ (sr & 7)) << 3);
    const float* afs0 = Af + (m0 + sr) * 1024 + sg * 8;
    const float* afs1 = afs0 + 16 * 1024;
    const bf16* bsrc0 = Bp + (n0 + sr) * 1024 + sg * 8;
    const bf16* bsrc1 = bsrc0 + 16 * 1024;
    const bf16* bsrc2 = bsrc0 + 32 * 1024;
    const bf16* bsrc3 = bsrc0 + 48 * 1024;

    float4 fa[4];
    fa[0] = *reinterpret_cast<const float4*>(afs0);
    fa[1] = *reinterpret_cast<const float4*>(afs0 + 4);
    fa[2] = *reinterpret_cast<const float4*>(afs1);
    fa[3] = *reinterpret_cast<const float4*>(afs1 + 4);
    bf16x8 b0 = ld8(bsrc0), b1 = ld8(bsrc1), b2 = ld8(bsrc2), b3 = ld8(bsrc3);
    for (int kt = 0; kt < nsteps; ++kt) {
        __syncthreads();  // previous step's reads complete
        *reinterpret_cast<bf16x8*>(&Al[st]) = cvt8(fa[0], fa[1]);
        *reinterpret_cast<bf16x8*>(&Al[st + 2048]) = cvt8(fa[2], fa[3]);
        *reinterpret_cast<bf16x8*>(&Bl[st]) = b0;
        *reinterpret_cast<bf16x8*>(&Bl[st + 2048]) = b1;
        *reinterpret_cast<bf16x8*>(&Bl[st + 4096]) = b2;
        *reinterpret_cast<bf16x8*>(&Bl[st + 6144]) = b3;
        __syncthreads();
        if (kt + 1 < nsteps) {  // prefetch next K-tile during compute
            const int k0 = (kt + 1) * 128;
            fa[0] = *reinterpret_cast<const float4*>(afs0 + k0);
            fa[1] = *reinterpret_cast<const float4*>(afs0 + k0 + 4);
            fa[2] = *reinterpret_cast<const float4*>(afs1 + k0);
            fa[3] = *reinterpret_cast<const float4*>(afs1 + k0 + 4);
            b0 = ld8(bsrc0 + k0);
            b1 = ld8(bsrc1 + k0);
            b2 = ld8(bsrc2 + k0);
            b3 = ld8(bsrc3 + k0);
        }
#pragma unroll
        for (int ks = 0; ks < 4; ++ks) {
            const int eo = ((ks * 4 + fg) ^ fx7) << 3;
            const bf16x8 af = ld8(&Al[(wrow + fr) * 128 + eo]);
            const bf16x8 bg0 = ld8(&Bl[(wcol + fr) * 128 + eo]);
            const bf16x8 bg1 = ld8(&Bl[(wcol + 16 + fr) * 128 + eo]);
            acc[0] = __builtin_amdgcn_mfma_f32_16x16x32_bf16(af, bg0, acc[0], 0, 0, 0);
            acc[1] = __builtin_amdgcn_mfma_f32_16x16x32_bf16(af, bg1, acc[1], 0, 0, 0);
        }
    }
}

// ------------- fused q/k/v projection: grid (4,32,6), 32x64 tiles ----------
__global__ __launch_bounds__(256) void proj_all(
    const float* __restrict__ x, const bf16* __restrict__ WqT,
    const bf16* __restrict__ WkT, const bf16* __restrict__ WvT,
    const float* __restrict__ qg, const float* __restrict__ qb,
    const float* __restrict__ qm, const float* __restrict__ qv,
    const float* __restrict__ vg, const float* __restrict__ vb,
    const float* __restrict__ vm, const float* __restrict__ vvar,
    bf16* __restrict__ Q2, float* __restrict__ kn, bf16* __restrict__ vbn) {
    const int z = blockIdx.z;
    const int m0 = blockIdx.y * 32;
    const int tid = threadIdx.x;
    const int w = tid >> 6, l = tid & 63;
    int n0, mode;
    const bf16* Bg;
    if (z < 4) { mode = 0; Bg = WqT; n0 = (z * 4 + blockIdx.x) * 64; }
    else if (z == 4) { mode = 1; Bg = WkT; n0 = blockIdx.x * 64; }
    else { mode = 2; Bg = WvT; n0 = blockIdx.x * 64; }
    __shared__ __align__(16) bf16 Al[4096];   // 8 KB
    __shared__ __align__(16) bf16 Bl[8192];   // 16 KB
    f32x4 acc[2] = {};
    kpass128f(x, Bg, Al, Bl, acc, m0, n0, 8);

    const int wrow = (w & 1) * 16, wcol = (w >> 1) * 32;
    const int drow = (l >> 4) * 4, dcol = l & 15;
#pragma unroll
    for (int ns = 0; ns < 2; ++ns) {
        const int gc = n0 + wcol + ns * 16 + dcol;
        float scale = 1.f, shift = 0.f;
        if (mode == 0) {
            scale = qg[gc] * rsqrtf(qv[gc] + 1e-3f);
            shift = qb[gc] - qm[gc] * scale;
        } else if (mode == 2) {
            scale = vg[gc] * rsqrtf(vvar[gc] + 1e-3f);
            shift = vb[gc] - vm[gc] * scale;
        }
#pragma unroll
        for (int r = 0; r < 4; ++r) {
            const int gr = m0 + wrow + drow + r;
            const float val = acc[ns][r] * scale + shift;
            if (mode == 0) {
                const int bh = gr >> 6;
                const int kk = (gr & 63) * 4 + (gc >> 8);
                Q2[bh * 65536 + (gc & 255) * 256 + kk] = (bf16)val;
            } else if (mode == 1) {
                kn[gr * 256 + gc] = val;
            } else {
                vbn[gr * 256 + gc] = (bf16)val;
            }
        }
    }
}

// ------- merged launch: LC (softmax + Lc GEMM) and S GEMM (R5 version) -----
__global__ __launch_bounds__(256) void lc_s(
    const float* __restrict__ kn, const bf16* __restrict__ vbn,
    const bf16* __restrict__ rpeb, const bf16* __restrict__ Q2,
    bf16* __restrict__ LcT, bf16* __restrict__ S) {
    __shared__ __align__(16) bf16 smem[20480];  // 40 KB
    const int tid = threadIdx.x;
    const int w = tid >> 6, l = tid & 63;
    const int fr = l & 15, fk = (l >> 4) * 8;
    const int fx = (fr & 7) << 3;

    if (blockIdx.y < 16) {  // ---------------- LC ----------------
        const int b = blockIdx.y >> 2;
        const int m0v = (blockIdx.y & 3) * 64;
        const int n0k = blockIdx.x * 64;
        bf16* Bfull = smem;
        bf16* Al = smem + 16384;

        const float* knb = kn + (b * 256 + n0k) * 256;
        const int row = tid >> 2, cq = (tid & 3) * 4;
        const float* src = knb + row * 256;
        float mx = -3.4e38f;
#pragma unroll
        for (int i = 0; i < 16; ++i) {
            const float4 v = *reinterpret_cast<const float4*>(&src[cq + i * 16]);
            mx = fmaxf(fmaxf(fmaxf(v.x, v.y), fmaxf(v.z, v.w)), mx);
        }
        mx = fmaxf(mx, __shfl_xor(mx, 1));
        mx = fmaxf(mx, __shfl_xor(mx, 2));
        float sum = 0.f;
#pragma unroll
        for (int i = 0; i < 16; ++i) {
            const float4 v = *reinterpret_cast<const float4*>(&src[cq + i * 16]);
            sum += expf(v.x - mx) + expf(v.y - mx) + expf(v.z - mx) + expf(v.w - mx);
        }
        sum += __shfl_xor(sum, 1);
        sum += __shfl_xor(sum, 2);
        const float inv = 1.f / sum;
#pragma unroll
        for (int i = 0; i < 16; ++i) {
            const int col = cq + i * 16;
            const float4 v = *reinterpret_cast<const float4*>(&src[col]);
            bf16 o[4] = {(bf16)(expf(v.x - mx) * inv), (bf16)(expf(v.y - mx) * inv),
                         (bf16)(expf(v.z - mx) * inv), (bf16)(expf(v.w - mx) * inv)};
            const int elem =
                row * 256 + ((((col >> 3) ^ (row & 7)) << 3) | (col & 7));
            *reinterpret_cast<uint2*>(&Bfull[elem]) = *reinterpret_cast<uint2*>(o);
        }

        const int sr0 = tid >> 3, sg = tid & 7;
        const int st0 = sr0 * 64 + ((sg ^ (sr0 & 7)) << 3);
        const int st1 = (sr0 + 32) * 64 + ((sg ^ (sr0 & 7)) << 3);
        const int wr = (w >> 1) * 32, wc = (w & 1) * 32;
        const bf16* va0 = vbn + (b * 256 + m0v + sr0) * 256 + sg * 8;
        const bf16* va1 = va0 + 32 * 256;
        bf16x8 a0 = ld8(va0), a1 = ld8(va1);
        f32x4 acc[2][2] = {};
        for (int kt = 0; kt < 4; ++kt) {
            __syncthreads();
            *reinterpret_cast<bf16x8*>(&Al[st0]) = a0;
            *reinterpret_cast<bf16x8*>(&Al[st1]) = a1;
            __syncthreads();
            if (kt + 1 < 4) {
                a0 = ld8(va0 + (kt + 1) * 64);
                a1 = ld8(va1 + (kt + 1) * 64);
            }
#pragma unroll
            for (int ks = 0; ks < 2; ++ks) {
                const int eoA = (ks * 32 + fk) ^ fx;
                const int eoB = (kt * 64 + ks * 32 + fk) ^ fx;
                const bf16x8 af0 = ld8(&Al[(wr + fr) * 64 + eoA]);
                const bf16x8 af1 = ld8(&Al[(wr + 16 + fr) * 64 + eoA]);
                const bf16x8 bg0 = ld8(&Bfull[(wc + fr) * 256 + eoB]);
                const bf16x8 bg1 = ld8(&Bfull[(wc + 16 + fr) * 256 + eoB]);
                acc[0][0] = __builtin_amdgcn_mfma_f32_16x16x32_bf16(af0, bg0, acc[0][0], 0, 0, 0);
                acc[0][1] = __builtin_amdgcn_mfma_f32_16x16x32_bf16(af0, bg1, acc[0][1], 0, 0, 0);
                acc[1][0] = __builtin_amdgcn_mfma_f32_16x16x32_bf16(af1, bg0, acc[1][0], 0, 0, 0);
                acc[1][1] = __builtin_amdgcn_mfma_f32_16x16x32_bf16(af1, bg1, acc[1][1], 0, 0, 0);
            }
        }
        const int drow = (l >> 4) * 4, dcol = l & 15;
#pragma unroll
        for (int ms = 0; ms < 2; ++ms)
#pragma unroll
            for (int ns = 0; ns < 2; ++ns)
#pragma unroll
                for (int r = 0; r < 4; ++r)
                    LcT[b * 65536 + (m0v + wr + ms * 16 + drow + r) * 256 + n0k +
                        wc + ns * 16 + dcol] = (bf16)acc[ms][ns][r];
        return;
    }

    // ---------------- S ----------------
    const int n = blockIdx.y - 16;
    const int m0 = blockIdx.x * 64;
    const int in_ = n >> 4, jn = n & 15;
    bf16* Als = smem;
    bf16* Bls = smem + 16384;
#pragma unroll
    for (int i = 0; i < 2; ++i) {
        const int slot = tid + i * 256;
        const int row = slot >> 5, g = slot & 31;
        *reinterpret_cast<bf16x8*>(&Bls[row * 256 + ((g ^ (row & 7)) << 3)]) =
            ld8(Q2 + row * 65536 + n * 256 + g * 8);
    }
#pragma unroll
    for (int i = 0; i < 8; ++i) {
        const int slot = tid + i * 256;
        const int row = slot >> 5, g = slot & 31;
        const int m = m0 + row;
        const int ridx = ((m >> 4) - in_ + 15) * 31 + ((m & 15) - jn + 15);
        *reinterpret_cast<bf16x8*>(&Als[row * 256 + ((g ^ (row & 7)) << 3)]) =
            ld8(rpeb + ridx * 256 + g * 8);
    }
    __syncthreads();
    f32x4 acc = {};
#pragma unroll
    for (int ks = 0; ks < 8; ++ks) {
        const int eo = (ks * 32 + fk) ^ fx;
        const bf16x8 af = ld8(&Als[(w * 16 + fr) * 256 + eo]);
        const bf16x8 bg = ld8(&Bls[fr * 256 + eo]);
        acc = __builtin_amdgcn_mfma_f32_16x16x32_bf16(af, bg, acc, 0, 0, 0);
    }
    const int drow = (l >> 4) * 4, bh = l & 15;
#pragma unroll
    for (int r = 0; r < 4; ++r) {
        const int m = m0 + w * 16 + drow + r;
        S[n * 4096 + bh * 256 + m] = (bf16)acc[r];
    }
}

// ---- MFMA K-pass, 32x64 tile, BK=128, bf16 A (R12 version, for yfinal) ----
template <int PA, int PB>
__device__ __forceinline__ void kpass128(const bf16* __restrict__ Ap, int offA,
                                         const bf16* __restrict__ Bp,
                                         bf16* __restrict__ Al, bf16* __restrict__ Bl,
                                         f32x4 (&acc)[2], int m0, int n0,
                                         int nsteps) {
    const int tid = threadIdx.x;
    const int w = tid >> 6, l = tid & 63;
    const int sr = tid >> 4;
    const int sg = tid & 15;
    const int wrow = (w & 1) * 16, wcol = (w >> 1) * 32;
    const int fr = l & 15, fg = l >> 4;
    const int fx7 = fr & 7;
    const int st = sr * 128 + ((sg ^ (sr & 7)) << 3);
    const bf16* asrc0 = Ap + (m0 + sr) * PA + offA + sg * 8;
    const bf16* asrc1 = asrc0 + 16 * PA;
    const bf16* bsrc0 = Bp + (n0 + sr) * PB + sg * 8;
    const bf16* bsrc1 = bsrc0 + 16 * PB;
    const bf16* bsrc2 = bsrc0 + 32 * PB;
    const bf16* bsrc3 = bsrc0 + 48 * PB;

    bf16x8 a0 = ld8(asrc0), a1 = ld8(asrc1);
    bf16x8 b0 = ld8(bsrc0), b1 = ld8(bsrc1), b2 = ld8(bsrc2), b3 = ld8(bsrc3);
    for (int kt = 0; kt < nsteps; ++kt) {
        __syncthreads();
        *reinterpret_cast<bf16x8*>(&Al[st]) = a0;
        *reinterpret_cast<bf16x8*>(&Al[st + 2048]) = a1;
        *reinterpret_cast<bf16x8*>(&Bl[st]) = b0;
        *reinterpret_cast<bf16x8*>(&Bl[st + 2048]) = b1;
        *reinterpret_cast<bf16x8*>(&Bl[st + 4096]) = b2;
        *reinterpret_cast<bf16x8*>(&Bl[st + 6144]) = b3;
        __syncthreads();
        if (kt + 1 < nsteps) {
            const int k0 = (kt + 1) * 128;
            a0 = ld8(asrc0 + k0);
            a1 = ld8(asrc1 + k0);
            b0 = ld8(bsrc0 + k0);
            b1 = ld8(bsrc1 + k0);
            b2 = ld8(bsrc2 + k0);
            b3 = ld8(bsrc3 + k0);
        }
#pragma unroll
        for (int ks = 0; ks < 4; ++ks) {
            const int eo = ((ks * 4 + fg) ^ fx7) << 3;
            const bf16x8 af = ld8(&Al[(wrow + fr) * 128 + eo]);
            const bf16x8 bg0 = ld8(&Bl[(wcol + fr) * 128 + eo]);
            const bf16x8 bg1 = ld8(&Bl[(wcol + 16 + fr) * 128 + eo]);
            acc[0] = __builtin_amdgcn_mfma_f32_16x16x32_bf16(af, bg0, acc[0], 0, 0, 0);
            acc[1] = __builtin_amdgcn_mfma_f32_16x16x32_bf16(af, bg1, acc[1], 0, 0, 0);
        }
    }
}

// ------- final: out = Q2*LcT^T + S*vbn^T, 32x64 tiles, grid (4,8,16) -------
__global__ __launch_bounds__(256) void yfinal(const bf16* __restrict__ Q2,
                                              const bf16* __restrict__ LcT,
                                              float* __restrict__ out,
                                              const bf16* __restrict__ S,
                                              const bf16* __restrict__ vbn) {
    const int tid = threadIdx.x;
    const int w = tid >> 6, l = tid & 63;
    const int m0 = blockIdx.y * 32, n0 = blockIdx.x * 64;
    const int z = blockIdx.z;
    __shared__ __align__(16) bf16 Al[4096];
    __shared__ __align__(16) bf16 Bl[8192];
    f32x4 acc[2] = {};
    kpass128<256, 256>(Q2 + z * 65536, 0, LcT + (z >> 2) * 65536, Al, Bl, acc, m0,
                       n0, 2);
    kpass128<4096, 256>(S, z * 256, vbn + (z >> 2) * 65536, Al, Bl, acc, m0, n0, 2);

    const int wrow = (w & 1) * 16, wcol = (w >> 1) * 32;
    const int drow = (l >> 4) * 4, dcol = l & 15;
#pragma unroll
    for (int ns = 0; ns < 2; ++ns)
#pragma unroll
        for (int r = 0; r < 4; ++r)
            out[(z >> 2) * 262144 + (m0 + wrow + drow + r) * 1024 +
                (z & 3) * 256 + n0 + wcol + ns * 16 + dcol] = acc[ns][r];
}

extern "C" void kernel_launch(void* const* d_in, const int* in_sizes, int n_in,
                              void* d_out, int out_size, void* d_ws, size_t ws_size,
                              hipStream_t stream) {
    const float* x = (const float*)d_in[0];
    const float* Wq = (const float*)d_in[1];
    const float* Wk = (const float*)d_in[2];
    const float* Wv = (const float*)d_in[3];
    const float* qg = (const float*)d_in[4];
    const float* qb = (const float*)d_in[5];
    const float* qm = (const float*)d_in[6];
    const float* qv = (const float*)d_in[7];
    const float* vg = (const float*)d_in[8];
    const float* vb = (const float*)d_in[9];
    const float* vm = (const float*)d_in[10];
    const float* vvar = (const float*)d_in[11];
    const float* rpe = (const float*)d_in[12];
    float* out = (float*)d_out;

    char* wsb = (char*)d_ws;
    bf16* WqT = (bf16*)(wsb + 0x200000u);     // 2 MB
    bf16* WkT = (bf16*)(wsb + 0x400000u);     // 512 KB
    bf16* WvT = (bf16*)(wsb + 0x480000u);     // 512 KB
    bf16* rpeb = (bf16*)(wsb + 0x500000u);    // 492 KB
    bf16* Q2 = (bf16*)(wsb + 0x580000u);      // 2 MB
    bf16* vbn = (bf16*)(wsb + 0x800000u);     // 512 KB
    bf16* LcT = (bf16*)(wsb + 0x880000u);     // 512 KB
    bf16* S = (bf16*)(wsb + 0x900000u);       // 2 MB
    float* kn = (float*)(wsb + 0xB00000u);    // 1 MB

    const dim3 blk(256);
    prep<<<1597, blk, 0, stream>>>(Wq, Wk, Wv, rpe, WqT, WkT, WvT, rpeb);
    proj_all<<<dim3(4, 32, 6), blk, 0, stream>>>(x, WqT, WkT, WvT, qg, qb, qm, qv,
                                                 vg, vb, vm, vvar, Q2, kn, vbn);
    lc_s<<<dim3(4, 272), blk, 0, stream>>>(kn, vbn, rpeb, Q2, LcT, S);
    yfinal<<<dim3(4, 8, 16), blk, 0, stream>>>(Q2, LcT, out, S, vbn);
}

// Round 17
// 39.402 us; speedup vs baseline: 3.5045x; 1.0456x over previous
//
#include <hip/hip_runtime.h>

// LambdaLayer b=4, m=256 spatial, cin=1024, heads=4, dim_k=dim_v=256, u=1.
// f32 in/out; bf16 MFMA compute, f32 accum. LDS XOR-swizzle (granule^=row&7).
// R17 = R14 restored (verified best, 39.9us) + packed S store (R9-validated).
//   proj 32x64/BK=128 grid 768 (R11+R12 proven), lc_s R5, yfinal 32x64/BK=128.
// Ruled out empirically: gload_lds (R6), 64x64 tile (R13), persistent fusion
// (R15: spin-gridbar 55us), xb-elim (R16). 4 launches.

typedef __bf16 bf16;
typedef __attribute__((ext_vector_type(8))) __bf16 bf16x8;
typedef __attribute__((ext_vector_type(4))) float f32x4;

__device__ __forceinline__ bf16x8 ld8(const bf16* p) {
    return *reinterpret_cast<const bf16x8*>(p);
}

// ---------------- prep: casts + weight transposes, packed stores -----------
__global__ __launch_bounds__(256) void prep(
    const float* __restrict__ x, const float* __restrict__ Wq,
    const float* __restrict__ Wk, const float* __restrict__ Wv,
    const float* __restrict__ rpe, bf16* __restrict__ xb,
    bf16* __restrict__ WqT, bf16* __restrict__ WkT, bf16* __restrict__ WvT,
    bf16* __restrict__ rpeb) {
    __shared__ float tile[32][33];
    const int bid = blockIdx.x, tid = threadIdx.x;
    const float* W = nullptr;
    bf16* WT = nullptr;
    int ldw = 0, ci = 0, di = 0;
    if (bid < 1024) {
        W = Wq; WT = WqT; ldw = 1024; ci = bid >> 5; di = bid & 31;
    } else if (bid < 1280) {
        const int t2 = bid - 1024;
        W = Wk; WT = WkT; ldw = 256; ci = t2 >> 3; di = t2 & 7;
    } else if (bid < 1536) {
        const int t2 = bid - 1280;
        W = Wv; WT = WvT; ldw = 256; ci = t2 >> 3; di = t2 & 7;
    }
    if (W) {  // transpose-cast one 32x32 tile
        const int r = tid >> 3, c4 = (tid & 7) * 4;
        const float4 v =
            *reinterpret_cast<const float4*>(&W[(ci * 32 + r) * ldw + di * 32 + c4]);
        tile[r][c4 + 0] = v.x;
        tile[r][c4 + 1] = v.y;
        tile[r][c4 + 2] = v.z;
        tile[r][c4 + 3] = v.w;
        __syncthreads();
        bf16 o[4] = {(bf16)tile[c4 + 0][r], (bf16)tile[c4 + 1][r],
                     (bf16)tile[c4 + 2][r], (bf16)tile[c4 + 3][r]};
        *reinterpret_cast<uint2*>(&WT[(di * 32 + r) * 1024 + ci * 32 + c4]) =
            *reinterpret_cast<uint2*>(o);
        return;
    }
    if (bid < 1792) {  // xb cast
        const int base = (bid - 1536) * 1024 + tid;
        const float4* xs = reinterpret_cast<const float4*>(x);
#pragma unroll
        for (int j = 0; j < 4; ++j) {
            const float4 v = xs[base + j * 256];
            bf16 o[4] = {(bf16)v.x, (bf16)v.y, (bf16)v.z, (bf16)v.w};
            *reinterpret_cast<uint2*>(&xb[(base + j * 256) * 4]) =
                *reinterpret_cast<uint2*>(o);
        }
        return;
    }
    {  // rpeb cast
        const int base = (bid - 1792) * 1024 + tid;
        const float4* rs = reinterpret_cast<const float4*>(rpe);
#pragma unroll
        for (int j = 0; j < 4; ++j) {
            const int idx = base + j * 256;
            if (idx < 61504) {
                const float4 v = rs[idx];
                bf16 o[4] = {(bf16)v.x, (bf16)v.y, (bf16)v.z, (bf16)v.w};
                *reinterpret_cast<uint2*>(&rpeb[idx * 4]) =
                    *reinterpret_cast<uint2*>(o);
            }
        }
    }
}

// ---- MFMA K-pass, 32x64 tile, BK=128, 4 waves (R12-proven) ----------------
// A:[32][128] LDS 8KB, B:[64][128] 16KB, swizzled (granule ^= row&7).
// Wave w: rows (w&1)*16, cols (w>>1)*32. 8 MFMA/wave/step.
template <int PA, int PB>
__device__ __forceinline__ void kpass128(const bf16* __restrict__ Ap, int offA,
                                         const bf16* __restrict__ Bp,
                                         bf16* __restrict__ Al, bf16* __restrict__ Bl,
                                         f32x4 (&acc)[2], int m0, int n0,
                                         int nsteps) {
    const int tid = threadIdx.x;
    const int w = tid >> 6, l = tid & 63;
    const int sr = tid >> 4;   // staging row 0..15
    const int sg = tid & 15;   // granule 0..15
    const int wrow = (w & 1) * 16, wcol = (w >> 1) * 32;
    const int fr = l & 15, fg = l >> 4;
    const int fx7 = fr & 7;
    const int st = sr * 128 + ((sg ^ (sr & 7)) << 3);  // (sr+16k)&7 == sr&7
    const bf16* asrc0 = Ap + (m0 + sr) * PA + offA + sg * 8;
    const bf16* asrc1 = asrc0 + 16 * PA;
    const bf16* bsrc0 = Bp + (n0 + sr) * PB + sg * 8;
    const bf16* bsrc1 = bsrc0 + 16 * PB;
    const bf16* bsrc2 = bsrc0 + 32 * PB;
    const bf16* bsrc3 = bsrc0 + 48 * PB;

    bf16x8 a0 = ld8(asrc0), a1 = ld8(asrc1);
    bf16x8 b0 = ld8(bsrc0), b1 = ld8(bsrc1), b2 = ld8(bsrc2), b3 = ld8(bsrc3);
    for (int kt = 0; kt < nsteps; ++kt) {
        __syncthreads();  // previous step's reads complete
        *reinterpret_cast<bf16x8*>(&Al[st]) = a0;
        *reinterpret_cast<bf16x8*>(&Al[st + 2048]) = a1;
        *reinterpret_cast<bf16x8*>(&Bl[st]) = b0;
        *reinterpret_cast<bf16x8*>(&Bl[st + 2048]) = b1;
        *reinterpret_cast<bf16x8*>(&Bl[st + 4096]) = b2;
        *reinterpret_cast<bf16x8*>(&Bl[st + 6144]) = b3;
        __syncthreads();
        if (kt + 1 < nsteps) {  // prefetch next K-tile during compute
            const int k0 = (kt + 1) * 128;
            a0 = ld8(asrc0 + k0);
            a1 = ld8(asrc1 + k0);
            b0 = ld8(bsrc0 + k0);
            b1 = ld8(bsrc1 + k0);
            b2 = ld8(bsrc2 + k0);
            b3 = ld8(bsrc3 + k0);
        }
#pragma unroll
        for (int ks = 0; ks < 4; ++ks) {
            const int eo = ((ks * 4 + fg) ^ fx7) << 3;
            const bf16x8 af = ld8(&Al[(wrow + fr) * 128 + eo]);
            const bf16x8 bg0 = ld8(&Bl[(wcol + fr) * 128 + eo]);
            const bf16x8 bg1 = ld8(&Bl[(wcol + 16 + fr) * 128 + eo]);
            acc[0] = __builtin_amdgcn_mfma_f32_16x16x32_bf16(af, bg0, acc[0], 0, 0, 0);
            acc[1] = __builtin_amdgcn_mfma_f32_16x16x32_bf16(af, bg1, acc[1], 0, 0, 0);
        }
    }
}

// ------------- fused q/k/v projection: grid (4,32,6), 32x64 tiles ----------
__global__ __launch_bounds__(256) void proj_all(
    const bf16* __restrict__ xb, const bf16* __restrict__ WqT,
    const bf16* __restrict__ WkT, const bf16* __restrict__ WvT,
    const float* __restrict__ qg, const float* __restrict__ qb,
    const float* __restrict__ qm, const float* __restrict__ qv,
    const float* __restrict__ vg, const float* __restrict__ vb,
    const float* __restrict__ vm, const float* __restrict__ vvar,
    bf16* __restrict__ Q2, float* __restrict__ kn, bf16* __restrict__ vbn) {
    const int z = blockIdx.z;
    const int m0 = blockIdx.y * 32;
    const int tid = threadIdx.x;
    const int w = tid >> 6, l = tid & 63;
    int n0, mode;
    const bf16* Bg;
    if (z < 4) { mode = 0; Bg = WqT; n0 = (z * 4 + blockIdx.x) * 64; }
    else if (z == 4) { mode = 1; Bg = WkT; n0 = blockIdx.x * 64; }
    else { mode = 2; Bg = WvT; n0 = blockIdx.x * 64; }
    __shared__ __align__(16) bf16 Al[4096];   // 8 KB
    __shared__ __align__(16) bf16 Bl[8192];   // 16 KB
    f32x4 acc[2] = {};
    kpass128<1024, 1024>(xb, 0, Bg, Al, Bl, acc, m0, n0, 8);

    const int wrow = (w & 1) * 16, wcol = (w >> 1) * 32;
    const int drow = (l >> 4) * 4, dcol = l & 15;
#pragma unroll
    for (int ns = 0; ns < 2; ++ns) {
        const int gc = n0 + wcol + ns * 16 + dcol;
        float scale = 1.f, shift = 0.f;
        if (mode == 0) {
            scale = qg[gc] * rsqrtf(qv[gc] + 1e-3f);
            shift = qb[gc] - qm[gc] * scale;
        } else if (mode == 2) {
            scale = vg[gc] * rsqrtf(vvar[gc] + 1e-3f);
            shift = vb[gc] - vm[gc] * scale;
        }
#pragma unroll
        for (int r = 0; r < 4; ++r) {
            const int gr = m0 + wrow + drow + r;
            const float val = acc[ns][r] * scale + shift;
            if (mode == 0) {
                const int bh = gr >> 6;
                const int kk = (gr & 63) * 4 + (gc >> 8);
                Q2[bh * 65536 + (gc & 255) * 256 + kk] = (bf16)val;
            } else if (mode == 1) {
                kn[gr * 256 + gc] = val;
            } else {
                vbn[gr * 256 + gc] = (bf16)val;
            }
        }
    }
}

// ------- merged launch: LC (softmax + Lc GEMM) and S GEMM (R5 version) -----
__global__ __launch_bounds__(256) void lc_s(
    const float* __restrict__ kn, const bf16* __restrict__ vbn,
    const bf16* __restrict__ rpeb, const bf16* __restrict__ Q2,
    bf16* __restrict__ LcT, bf16* __restrict__ S) {
    __shared__ __align__(16) bf16 smem[20480];  // 40 KB
    const int tid = threadIdx.x;
    const int w = tid >> 6, l = tid & 63;
    const int fr = l & 15, fk = (l >> 4) * 8;
    const int fx = (fr & 7) << 3;

    if (blockIdx.y < 16) {  // ---------------- LC ----------------
        const int b = blockIdx.y >> 2;
        const int m0v = (blockIdx.y & 3) * 64;
        const int n0k = blockIdx.x * 64;
        bf16* Bfull = smem;
        bf16* Al = smem + 16384;

        const float* knb = kn + (b * 256 + n0k) * 256;
        const int row = tid >> 2, cq = (tid & 3) * 4;
        const float* src = knb + row * 256;
        float mx = -3.4e38f;
#pragma unroll
        for (int i = 0; i < 16; ++i) {
            const float4 v = *reinterpret_cast<const float4*>(&src[cq + i * 16]);
            mx = fmaxf(fmaxf(fmaxf(v.x, v.y), fmaxf(v.z, v.w)), mx);
        }
        mx = fmaxf(mx, __shfl_xor(mx, 1));
        mx = fmaxf(mx, __shfl_xor(mx, 2));
        float sum = 0.f;
#pragma unroll
        for (int i = 0; i < 16; ++i) {
            const float4 v = *reinterpret_cast<const float4*>(&src[cq + i * 16]);
            sum += expf(v.x - mx) + expf(v.y - mx) + expf(v.z - mx) + expf(v.w - mx);
        }
        sum += __shfl_xor(sum, 1);
        sum += __shfl_xor(sum, 2);
        const float inv = 1.f / sum;
#pragma unroll
        for (int i = 0; i < 16; ++i) {
            const int col = cq + i * 16;
            const float4 v = *reinterpret_cast<const float4*>(&src[col]);
            bf16 o[4] = {(bf16)(expf(v.x - mx) * inv), (bf16)(expf(v.y - mx) * inv),
                         (bf16)(expf(v.z - mx) * inv), (bf16)(expf(v.w - mx) * inv)};
            const int elem =
                row * 256 + ((((col >> 3) ^ (row & 7)) << 3) | (col & 7));
            *reinterpret_cast<uint2*>(&Bfull[elem]) = *reinterpret_cast<uint2*>(o);
        }

        const int sr0 = tid >> 3, sg = tid & 7;
        const int st0 = sr0 * 64 + ((sg ^ (sr0 & 7)) << 3);
        const int st1 = (sr0 + 32) * 64 + ((sg ^ (sr0 & 7)) << 3);
        const int wr = (w >> 1) * 32, wc = (w & 1) * 32;
        const bf16* va0 = vbn + (b * 256 + m0v + sr0) * 256 + sg * 8;
        const bf16* va1 = va0 + 32 * 256;
        bf16x8 a0 = ld8(va0), a1 = ld8(va1);
        f32x4 acc[2][2] = {};
        for (int kt = 0; kt < 4; ++kt) {
            __syncthreads();
            *reinterpret_cast<bf16x8*>(&Al[st0]) = a0;
            *reinterpret_cast<bf16x8*>(&Al[st1]) = a1;
            __syncthreads();
            if (kt + 1 < 4) {
                a0 = ld8(va0 + (kt + 1) * 64);
                a1 = ld8(va1 + (kt + 1) * 64);
            }
#pragma unroll
            for (int ks = 0; ks < 2; ++ks) {
                const int eoA = (ks * 32 + fk) ^ fx;
                const int eoB = (kt * 64 + ks * 32 + fk) ^ fx;
                const bf16x8 af0 = ld8(&Al[(wr + fr) * 64 + eoA]);
                const bf16x8 af1 = ld8(&Al[(wr + 16 + fr) * 64 + eoA]);
                const bf16x8 bg0 = ld8(&Bfull[(wc + fr) * 256 + eoB]);
                const bf16x8 bg1 = ld8(&Bfull[(wc + 16 + fr) * 256 + eoB]);
                acc[0][0] = __builtin_amdgcn_mfma_f32_16x16x32_bf16(af0, bg0, acc[0][0], 0, 0, 0);
                acc[0][1] = __builtin_amdgcn_mfma_f32_16x16x32_bf16(af0, bg1, acc[0][1], 0, 0, 0);
                acc[1][0] = __builtin_amdgcn_mfma_f32_16x16x32_bf16(af1, bg0, acc[1][0], 0, 0, 0);
                acc[1][1] = __builtin_amdgcn_mfma_f32_16x16x32_bf16(af1, bg1, acc[1][1], 0, 0, 0);
            }
        }
        const int drow = (l >> 4) * 4, dcol = l & 15;
#pragma unroll
        for (int ms = 0; ms < 2; ++ms)
#pragma unroll
            for (int ns = 0; ns < 2; ++ns)
#pragma unroll
                for (int r = 0; r < 4; ++r)
                    LcT[b * 65536 + (m0v + wr + ms * 16 + drow + r) * 256 + n0k +
                        wc + ns * 16 + dcol] = (bf16)acc[ms][ns][r];
        return;
    }

    // ---------------- S ----------------
    const int n = blockIdx.y - 16;
    const int m0 = blockIdx.x * 64;
    const int in_ = n >> 4, jn = n & 15;
    bf16* Als = smem;
    bf16* Bls = smem + 16384;
#pragma unroll
    for (int i = 0; i < 2; ++i) {
        const int slot = tid + i * 256;
        const int row = slot >> 5, g = slot & 31;
        *reinterpret_cast<bf16x8*>(&Bls[row * 256 + ((g ^ (row & 7)) << 3)]) =
            ld8(Q2 + row * 65536 + n * 256 + g * 8);
    }
#pragma unroll
    for (int i = 0; i < 8; ++i) {
        const int slot = tid + i * 256;
        const int row = slot >> 5, g = slot & 31;
        const int m = m0 + row;
        const int ridx = ((m >> 4) - in_ + 15) * 31 + ((m & 15) - jn + 15);
        *reinterpret_cast<bf16x8*>(&Als[row * 256 + ((g ^ (row & 7)) << 3)]) =
            ld8(rpeb + ridx * 256 + g * 8);
    }
    __syncthreads();
    f32x4 acc = {};
#pragma unroll
    for (int ks = 0; ks < 8; ++ks) {
        const int eo = (ks * 32 + fk) ^ fx;
        const bf16x8 af = ld8(&Als[(w * 16 + fr) * 256 + eo]);
        const bf16x8 bg = ld8(&Bls[fr * 256 + eo]);
        acc = __builtin_amdgcn_mfma_f32_16x16x32_bf16(af, bg, acc, 0, 0, 0);
    }
    const int drow = (l >> 4) * 4, bh = l & 15;
    bf16 o[4] = {(bf16)acc[0], (bf16)acc[1], (bf16)acc[2], (bf16)acc[3]};
    *reinterpret_cast<uint2*>(&S[n * 4096 + bh * 256 + m0 + w * 16 + drow]) =
        *reinterpret_cast<uint2*>(o);
}

// ------- final: out = Q2*LcT^T + S*vbn^T, 32x64 tiles, grid (4,8,16) -------
__global__ __launch_bounds__(256) void yfinal(const bf16* __restrict__ Q2,
                                              const bf16* __restrict__ LcT,
                                              float* __restrict__ out,
                                              const bf16* __restrict__ S,
                                              const bf16* __restrict__ vbn) {
    const int tid = threadIdx.x;
    const int w = tid >> 6, l = tid & 63;
    const int m0 = blockIdx.y * 32, n0 = blockIdx.x * 64;
    const int z = blockIdx.z;
    __shared__ __align__(16) bf16 Al[4096];
    __shared__ __align__(16) bf16 Bl[8192];
    f32x4 acc[2] = {};
    kpass128<256, 256>(Q2 + z * 65536, 0, LcT + (z >> 2) * 65536, Al, Bl, acc, m0,
                       n0, 2);
    kpass128<4096, 256>(S, z * 256, vbn + (z >> 2) * 65536, Al, Bl, acc, m0, n0, 2);

    const int wrow = (w & 1) * 16, wcol = (w >> 1) * 32;
    const int drow = (l >> 4) * 4, dcol = l & 15;
#pragma unroll
    for (int ns = 0; ns < 2; ++ns)
#pragma unroll
        for (int r = 0; r < 4; ++r)
            out[(z >> 2) * 262144 + (m0 + wrow + drow + r) * 1024 +
                (z & 3) * 256 + n0 + wcol + ns * 16 + dcol] = acc[ns][r];
}

extern "C" void kernel_launch(void* const* d_in, const int* in_sizes, int n_in,
                              void* d_out, int out_size, void* d_ws, size_t ws_size,
                              hipStream_t stream) {
    const float* x = (const float*)d_in[0];
    const float* Wq = (const float*)d_in[1];
    const float* Wk = (const float*)d_in[2];
    const float* Wv = (const float*)d_in[3];
    const float* qg = (const float*)d_in[4];
    const float* qb = (const float*)d_in[5];
    const float* qm = (const float*)d_in[6];
    const float* qv = (const float*)d_in[7];
    const float* vg = (const float*)d_in[8];
    const float* vb = (const float*)d_in[9];
    const float* vm = (const float*)d_in[10];
    const float* vvar = (const float*)d_in[11];
    const float* rpe = (const float*)d_in[12];
    float* out = (float*)d_out;

    char* wsb = (char*)d_ws;
    bf16* xb = (bf16*)(wsb);                  // 2 MB
    bf16* WqT = (bf16*)(wsb + 0x200000u);     // 2 MB
    bf16* WkT = (bf16*)(wsb + 0x400000u);     // 512 KB
    bf16* WvT = (bf16*)(wsb + 0x480000u);     // 512 KB
    bf16* rpeb = (bf16*)(wsb + 0x500000u);    // 492 KB
    bf16* Q2 = (bf16*)(wsb + 0x580000u);      // 2 MB
    bf16* vbn = (bf16*)(wsb + 0x800000u);     // 512 KB
    bf16* LcT = (bf16*)(wsb + 0x880000u);     // 512 KB
    bf16* S = (bf16*)(wsb + 0x900000u);       // 2 MB
    float* kn = (float*)(wsb + 0xB00000u);    // 1 MB

    const dim3 blk(256);
    prep<<<1853, blk, 0, stream>>>(x, Wq, Wk, Wv, rpe, xb, WqT, WkT, WvT, rpeb);
    proj_all<<<dim3(4, 32, 6), blk, 0, stream>>>(xb, WqT, WkT, WvT, qg, qb, qm, qv,
                                                 vg, vb, vm, vvar, Q2, kn, vbn);
    lc_s<<<dim3(4, 272), blk, 0, stream>>>(kn, vbn, rpeb, Q2, LcT, S);
    yfinal<<<dim3(4, 8, 16), blk, 0, stream>>>(Q2, LcT, out, S, vbn);
}